// Round 3
// baseline (253.561 us; speedup 1.0000x reference)
//
#include <hip/hip_runtime.h>
#include <stdint.h>

// BATCH=4096, LENGTH=128, FEAT=4, RANK=64, 126 mid sites.
#define NSITES 126

typedef _Float16 half8_t  __attribute__((ext_vector_type(8)));
typedef _Float16 half2_t  __attribute__((ext_vector_type(2)));
typedef float    float4_t __attribute__((ext_vector_type(4)));
typedef uint32_t uint4_t  __attribute__((ext_vector_type(4)));

// ---------------------------------------------------------------------------
// Repack mid_cores fp32 [126][64][4][64] -> fp16 fragments, frag F (16B):
// element j = G[l = 32h + 8q + j][n = i*64 + w*16 + c], lane = 16q + c,
// F = ((i*2+h)*4 + w)*64 + lane  (+ s*2048). Unchanged from R1 (verified).
// Serves as the A-operand of G^T: A[m = lane&15][k = 8(lane>>4)+j], per the
// R0-hardware-verified A/B/C fragment mappings.
// ---------------------------------------------------------------------------
__global__ __launch_bounds__(256) void repack_g(const float* __restrict__ mid,
                                                _Float16* __restrict__ gt) {
    const int F = blockIdx.x * 256 + threadIdx.x;          // 0..258047 == 126*2048
    const int lane = F & 63, w = (F >> 6) & 3, h = (F >> 8) & 1, i = (F >> 9) & 3;
    const int s = F >> 11;
    const int q = lane >> 4, c = lane & 15;
    const float* src = mid + (size_t)s * 16384 + (32 * h + 8 * q) * 256 + i * 64 + w * 16 + c;
    half8_t o;
#pragma unroll
    for (int j = 0; j < 8; ++j) o[j] = (_Float16)src[j * 256];
    ((half8_t*)gt)[F] = o;
}

// ---------------------------------------------------------------------------
// Barrier-free chain, swapped-operand form. One wave per block; each wave
// runs TWO independent 16-batch groups (a,b) which share the per-site G
// fragments (loaded once -> halves chip G traffic). State u = v^T held in
// B-frag layout per group: lane(q,c): u0[j]=v[batch c][8q+j], u1[j]=v[c][32+8q+j].
// Per site per group:
//   acc[f][m] = mfma(Gfrag[f,kh=0,m], u0) ; += mfma(Gfrag[f,kh=1,m], u1)
//   wv[m][r]  = sum_f x[b,s+1,f] * acc[f][m][r]      ( = v'[c][16m+4q+r] )
//   u' <- 16 ds_bpermute + 8 cndmask in-register C->B transpose
// Plain loads only: compiler owns all waitcnt/hazard/spill bookkeeping.
// Double-buffered G (E/O) software-pipelines one site ahead.
// 128 blocks x 64 threads: 1 wave/CU, VMEM-return-bound (~590 cyc/site).
// ---------------------------------------------------------------------------
__global__ __launch_bounds__(64, 1) void tt_chain(
    const float* __restrict__ x,      // [4096][128][4]
    const float* __restrict__ first,  // [4][64]
    const float* __restrict__ last,   // [64][4]
    const _Float16* __restrict__ gt,  // frag-ordered fp16, 32 KB/site
    float* __restrict__ out) {        // [4096]

    const int lane = threadIdx.x;     // 0..63
    const int q    = lane >> 4;
    const int c    = lane & 15;
    const int ba   = blockIdx.x * 32 + c;        // group a batch
    const int bb   = ba + 16;                    // group b batch
    const int msel = lane >> 5;                  // = q>>1: m-tile parity select

    // bpermute byte-indices (constant per lane): pull from lane (qs, c),
    // qs = 2(q&1) for dwords 0..1, qs = 2(q&1)+1 for dwords 2..3.
    const int srcA4 = ((q & 1) << 7) + (c << 2);
    const int srcB4 = srcA4 + 64;

    // ---- prologue: v0 in B-frag layout, per group ----
    half8_t u0a, u1a, u0b, u1b;
    auto PRO = [&](int b, half8_t& u0, half8_t& u1) {
        const float4_t x0 = *(const float4_t*)(x + (size_t)b * 512);
        float u0f[8] = {0, 0, 0, 0, 0, 0, 0, 0}, u1f[8] = {0, 0, 0, 0, 0, 0, 0, 0};
#pragma unroll
        for (int f = 0; f < 4; ++f) {
            const float xf = x0[f];
            const float* fp = first + f * 64 + 8 * q;
            const float4_t a0 = *(const float4_t*)(fp);
            const float4_t a1 = *(const float4_t*)(fp + 4);
            const float4_t a2 = *(const float4_t*)(fp + 32);
            const float4_t a3 = *(const float4_t*)(fp + 36);
#pragma unroll
            for (int j = 0; j < 4; ++j) {
                u0f[j] += xf * a0[j];  u0f[4 + j] += xf * a1[j];
                u1f[j] += xf * a2[j]; u1f[4 + j] += xf * a3[j];
            }
        }
#pragma unroll
        for (int j = 0; j < 8; ++j) { u0[j] = (_Float16)u0f[j]; u1[j] = (_Float16)u1f[j]; }
    };
    PRO(ba, u0a, u1a);
    PRO(bb, u0b, u1b);

    const half8_t* g8 = (const half8_t*)gt;      // frag(s,k) at g8[s*2048 + k*64 + lane]

    half8_t E[32], O[32];
    float4_t xea, xeb, xoa, xob;

    // preload site 0 + x_for(0) = x[b][1]
    {
        const half8_t* gp = g8 + lane;
#pragma unroll
        for (int k = 0; k < 32; ++k) E[k] = gp[k * 64];
        xea = *(const float4_t*)(x + (size_t)ba * 512 + 4);
        xeb = *(const float4_t*)(x + (size_t)bb * 512 + 4);
    }

    int eta = 0, etb = 0;                        // per-lane exponent accumulators

    // one group's site step on the CUR fragments
    auto GRP = [&](int s, const half8_t (&CUR)[32], const float4_t& xc,
                   half8_t& u0, half8_t& u1, int& etot) {
        float4_t acc[4][4];
#pragma unroll
        for (int f = 0; f < 4; ++f)
#pragma unroll
            for (int m = 0; m < 4; ++m) {
                float4_t z = {0.f, 0.f, 0.f, 0.f};
                z = __builtin_amdgcn_mfma_f32_16x16x32_f16(CUR[f * 8 + m],     u0, z, 0, 0, 0);
                z = __builtin_amdgcn_mfma_f32_16x16x32_f16(CUR[f * 8 + 4 + m], u1, z, 0, 0, 0);
                acc[f][m] = z;
            }

        // combine with physical leg: wv[m][r] = v'[batch c][16m + 4q + r]
        float wv[4][4];
#pragma unroll
        for (int m = 0; m < 4; ++m)
#pragma unroll
            for (int r = 0; r < 4; ++r)
                wv[m][r] = xc[0] * acc[0][m][r] + xc[1] * acc[1][m][r] +
                           xc[2] * acc[2][m][r] + xc[3] * acc[3][m][r];

        // per-batch power-of-2 renorm every 4 sites (fp16 overflow insurance)
        if ((s & 3) == 3 && s != NSITES - 1) {
            float mx = 0.f;
#pragma unroll
            for (int m = 0; m < 4; ++m)
#pragma unroll
                for (int r = 0; r < 4; ++r) mx = fmaxf(mx, fabsf(wv[m][r]));
            mx = fmaxf(mx, __shfl_xor(mx, 16));  // butterfly over q: full r-range max
            mx = fmaxf(mx, __shfl_xor(mx, 32));
            int e = 0;
            if (mx > 0.f) frexpf(mx, &e);
            const float sc = ldexpf(1.0f, -e);
#pragma unroll
            for (int m = 0; m < 4; ++m)
#pragma unroll
                for (int r = 0; r < 4; ++r) wv[m][r] *= sc;
            etot += e;
        }

        // pack (RNE) to fp16 pairs: h2[m][hh] = {wv[m][2hh], wv[m][2hh+1]}
        uint32_t h2[4][2];
#pragma unroll
        for (int m = 0; m < 4; ++m) {
            half2_t p0 = { (_Float16)wv[m][0], (_Float16)wv[m][1] };
            half2_t p1 = { (_Float16)wv[m][2], (_Float16)wv[m][3] };
            h2[m][0] = __builtin_bit_cast(uint32_t, p0);
            h2[m][1] = __builtin_bit_cast(uint32_t, p1);
        }

        // exchange C-layout -> next-site B-frags: target u_kh[j] = v'[c][32kh+8q+j];
        // value v'[c][16m+4qs+r] lives at lane (qs,c) h2[m][r>>1]. m = 2kh + (q>>1).
#pragma unroll
        for (int kh = 0; kh < 2; ++kh) {
            const int m0 = 2 * kh, m1 = 2 * kh + 1;
            const int a0  = __builtin_amdgcn_ds_bpermute(srcA4, (int)h2[m0][0]);
            const int a1  = __builtin_amdgcn_ds_bpermute(srcA4, (int)h2[m1][0]);
            const int a0b = __builtin_amdgcn_ds_bpermute(srcA4, (int)h2[m0][1]);
            const int a1b = __builtin_amdgcn_ds_bpermute(srcA4, (int)h2[m1][1]);
            const int b0_ = __builtin_amdgcn_ds_bpermute(srcB4, (int)h2[m0][0]);
            const int b1_ = __builtin_amdgcn_ds_bpermute(srcB4, (int)h2[m1][0]);
            const int b0b = __builtin_amdgcn_ds_bpermute(srcB4, (int)h2[m0][1]);
            const int b1b = __builtin_amdgcn_ds_bpermute(srcB4, (int)h2[m1][1]);
            uint4_t uu;
            uu[0] = (uint32_t)(msel ? a1  : a0);
            uu[1] = (uint32_t)(msel ? a1b : a0b);
            uu[2] = (uint32_t)(msel ? b1_ : b0_);
            uu[3] = (uint32_t)(msel ? b1b : b0b);
            if (kh == 0) u0 = __builtin_bit_cast(half8_t, uu);
            else         u1 = __builtin_bit_cast(half8_t, uu);
        }
    };

    // one site: prefetch next site's frags + x, then run both groups on CUR.
    // Loads of NXT are consumed one body later -> compiler-inserted counted
    // waits give a full site body of latency hiding.
    auto BODY = [&](int s, const half8_t (&CUR)[32], half8_t (&NXT)[32],
                    const float4_t& xca, const float4_t& xcb,
                    float4_t& xna, float4_t& xnb) {
        const int sn = (s + 1 < NSITES) ? s + 1 : NSITES - 1;
        const half8_t* gp = g8 + (size_t)sn * 2048 + lane;
#pragma unroll
        for (int k = 0; k < 32; ++k) NXT[k] = gp[k * 64];
        xna = *(const float4_t*)(x + (size_t)ba * 512 + (s + 2) * 4);   // x[b][s+2], max 127
        xnb = *(const float4_t*)(x + (size_t)bb * 512 + (s + 2) * 4);
        GRP(s, CUR, xca, u0a, u1a, eta);
        GRP(s, CUR, xcb, u0b, u1b, etb);
    };

    for (int s = 0; s < NSITES; s += 2) {
        BODY(s,     E, O, xea, xeb, xoa, xob);
        BODY(s + 1, O, E, xoa, xob, xea, xeb);
    }
    // after BODY(125): xea/xeb = x[b][127] (loaded at offset (125+2)*4 = 508)

    // out[b] = 2^etot * sum_r v[b][r] * (last[r,:] . x[b,127,:])
    auto FIN = [&](const half8_t& u0, const half8_t& u1, const float4_t& xl,
                   int etot, int b) {
        float dot = 0.f;
#pragma unroll
        for (int j = 0; j < 8; ++j) {
            const int r0 = 8 * q + j, r1 = 32 + 8 * q + j;
            const float4_t l0 = *(const float4_t*)(last + r0 * 4);
            const float4_t l1 = *(const float4_t*)(last + r1 * 4);
            const float lv0 = l0[0] * xl[0] + l0[1] * xl[1] + l0[2] * xl[2] + l0[3] * xl[3];
            const float lv1 = l1[0] * xl[0] + l1[1] * xl[1] + l1[2] * xl[2] + l1[3] * xl[3];
            dot += (float)u0[j] * lv0 + (float)u1[j] * lv1;
        }
        dot += __shfl_xor(dot, 16);   // sum over q: covers all r = 0..63
        dot += __shfl_xor(dot, 32);
        if (q == 0) out[b] = ldexpf(dot, etot);
    };
    FIN(u0a, u1a, xea, eta, ba);
    FIN(u0b, u1b, xeb, etb, bb);
}

extern "C" void kernel_launch(void* const* d_in, const int* in_sizes, int n_in,
                              void* d_out, int out_size, void* d_ws, size_t ws_size,
                              hipStream_t stream) {
    (void)in_sizes; (void)n_in; (void)out_size; (void)ws_size;
    const float* x     = (const float*)d_in[0];
    const float* first = (const float*)d_in[1];
    const float* mid   = (const float*)d_in[2];
    const float* last  = (const float*)d_in[3];
    float* out = (float*)d_out;
    _Float16* gt = (_Float16*)d_ws;   // 126*2048*16 B = 4,128,768 B

    repack_g<<<1008, 256, 0, stream>>>(mid, gt);
    tt_chain<<<128, 64, 0, stream>>>(x, first, last, gt, out);
}

// Round 7
// 253.276 us; speedup vs baseline: 1.0011x; 1.0011x over previous
//
#include <hip/hip_runtime.h>
#include <stdint.h>

// BATCH=4096, LENGTH=128, FEAT=4, RANK=64, 126 mid sites.
#define NSITES 126

typedef _Float16 half8_t  __attribute__((ext_vector_type(8)));
typedef _Float16 half2_t  __attribute__((ext_vector_type(2)));
typedef float    float4_t __attribute__((ext_vector_type(4)));
typedef uint32_t uint4_t  __attribute__((ext_vector_type(4)));

// explicit waits; memory clobber = compiler fence for all memory ops
#define WAITV(N) asm volatile("s_waitcnt vmcnt(" #N ")" ::: "memory")
#define WAITL()  asm volatile("s_waitcnt lgkmcnt(0)" ::: "memory")

// global->LDS DMA, 16B/lane: LDS dest = wave-uniform base + lane*16 (linear),
// global src = per-lane. No VGPR destination -> immune to the regalloc
// live-range-split corruption implicated in R2/R6 (in-flight asm dests).
__device__ __forceinline__ void gstage16(const void* g, void* l) {
    __builtin_amdgcn_global_load_lds(
        (const __attribute__((address_space(1))) void*)g,
        (__attribute__((address_space(3))) void*)l, 16, 0, 0);
}

// 32-bit LDS byte offset of a generic pointer into LDS
__device__ __forceinline__ uint32_t lds_off(const void* p) {
    return (uint32_t)(uintptr_t)(const __attribute__((address_space(3))) void*)p;
}

// asm LDS read with compile-time offset immediate: manual lgkm ledger,
// so the compiler inserts no conservative vmcnt waits against the DMA.
__device__ __forceinline__ void lread(half8_t& d, uint32_t base, int imm) {
    asm volatile("ds_read_b128 %0, %1 offset:%c2" : "=v"(d) : "v"(base), "i"(imm));
}

// ---------------------------------------------------------------------------
// Repack mid_cores fp32 [126][64][4][64] -> fp16 fragments, frag F (16B):
// element j = G[l = 32h + 8q + j][n = i*64 + w*16 + c], lane = 16q + c,
// F = ((i*2+h)*4 + w)*64 + lane  (+ s*2048). HW-verified (R0/R3 passes).
// ---------------------------------------------------------------------------
__global__ __launch_bounds__(256) void repack_g(const float* __restrict__ mid,
                                                _Float16* __restrict__ gt) {
    const int F = blockIdx.x * 256 + threadIdx.x;          // 0..258047 == 126*2048
    const int lane = F & 63, w = (F >> 6) & 3, h = (F >> 8) & 1, i = (F >> 9) & 3;
    const int s = F >> 11;
    const int q = lane >> 4, c = lane & 15;
    const float* src = mid + (size_t)s * 16384 + (32 * h + 8 * q) * 256 + i * 64 + w * 16 + c;
    half8_t o;
#pragma unroll
    for (int j = 0; j < 8; ++j) o[j] = (_Float16)src[j * 256];
    ((half8_t*)gt)[F] = o;
}

// ---------------------------------------------------------------------------
// Chain kernel: 128 blocks x 64 threads (1 wave/block). Each wave runs TWO
// independent 16-batch groups (A,B) sharing the per-site G tile — per-CU
// VMEM return (~64 B/cyc, measured by R0 at 513 cyc per 32KB site) is the
// bottleneck, so one delivered site serves 32 batches.
// Math = R3's HW-verified swapped-operand form, VERBATIM (f32 combine, fp16
// state, bpermute C->B exchange, renorm every 4 sites). The ONLY new
// mechanism vs R3 is G delivery: global_load_lds DMA into a 2x32KB LDS
// double buffer (prefetch distance 1 site, WAITV(0) at the site boundary),
// consumed by asm ds_read_b128 + lgkmcnt(0) + sched_barrier (rule #18).
// ---------------------------------------------------------------------------
__global__ __launch_bounds__(64, 1) void tt_chain(
    const float* __restrict__ x,      // [4096][128][4]
    const float* __restrict__ first,  // [4][64]
    const float* __restrict__ last,   // [64][4]
    const _Float16* __restrict__ gt,  // frag-ordered fp16, 32 KB/site
    float* __restrict__ out) {        // [4096]

    __shared__ __align__(16) char ldsG[2][32768];

    const int lane = threadIdx.x;     // 0..63
    const int q    = lane >> 4;
    const int c    = lane & 15;
    const int b0   = blockIdx.x * 32;
    const int ba   = b0 + c;                     // group A batch
    const int bb   = b0 + 16 + c;                // group B batch
    const int msel = lane >> 5;                  // m-tile parity select

    // bpermute byte-indices (constant per lane) — verbatim R3 (HW-verified)
    const int srcA4 = ((q & 1) << 7) + (c << 2);
    const int srcB4 = srcA4 + 64;

    // stage one site's 32 frags (32 KB) via DMA; src/dst both linear
    auto STAGE = [&](int site, int buf) {
        const char* gp = (const char*)gt + (size_t)site * 32768 + lane * 16;
        char* lp = &ldsG[buf][0];
#pragma unroll
        for (int k = 0; k < 32; ++k) gstage16(gp + k * 1024, lp + k * 1024);
    };

    STAGE(0, 0);   // site 0 DMA overlaps the prologue below

    // ---- v0 prologue in B-frag layout (plain loads, fully consumed) ----
    half8_t u0A, u1A, u0B, u1B;
    auto PRO = [&](int b, half8_t& u0, half8_t& u1) {
        const float4_t x0 = *(const float4_t*)(x + (size_t)b * 512);
        float u0f[8] = {0, 0, 0, 0, 0, 0, 0, 0}, u1f[8] = {0, 0, 0, 0, 0, 0, 0, 0};
#pragma unroll
        for (int f = 0; f < 4; ++f) {
            const float xf = x0[f];
            const float* fp = first + f * 64 + 8 * q;
            const float4_t a0 = *(const float4_t*)(fp);
            const float4_t a1 = *(const float4_t*)(fp + 4);
            const float4_t a2 = *(const float4_t*)(fp + 32);
            const float4_t a3 = *(const float4_t*)(fp + 36);
#pragma unroll
            for (int j = 0; j < 4; ++j) {
                u0f[j] += xf * a0[j];  u0f[4 + j] += xf * a1[j];
                u1f[j] += xf * a2[j]; u1f[4 + j] += xf * a3[j];
            }
        }
#pragma unroll
        for (int j = 0; j < 8; ++j) { u0[j] = (_Float16)u0f[j]; u1[j] = (_Float16)u1f[j]; }
    };
    PRO(ba, u0A, u1A);
    PRO(bb, u0B, u1B);

    float4_t xhA = *(const float4_t*)(x + (size_t)ba * 512 + 4);   // x[b][1]
    float4_t xhB = *(const float4_t*)(x + (size_t)bb * 512 + 4);

    const uint32_t lds0 = lds_off(&ldsG[0][0]) + lane * 16;
    const uint32_t lds1 = lds_off(&ldsG[1][0]) + lane * 16;

    int etA = 0, etB = 0;
    int cur = 0;

    // per-group site epilogue: f32 combine + renorm (1/4 sites) + pack +
    // C->B exchange — verbatim R3 (HW-verified)
    auto EPI = [&](int s, float4_t (&acc)[4][4], const float4_t& xc,
                   half8_t& u0, half8_t& u1, int& etot) {
        float wv[4][4];
#pragma unroll
        for (int m = 0; m < 4; ++m)
#pragma unroll
            for (int r = 0; r < 4; ++r)
                wv[m][r] = xc[0] * acc[0][m][r] + xc[1] * acc[1][m][r] +
                           xc[2] * acc[2][m][r] + xc[3] * acc[3][m][r];
        if ((s & 3) == 3 && s != NSITES - 1) {
            float mx = 0.f;
#pragma unroll
            for (int m = 0; m < 4; ++m)
#pragma unroll
                for (int r = 0; r < 4; ++r) mx = fmaxf(mx, fabsf(wv[m][r]));
            mx = fmaxf(mx, __shfl_xor(mx, 16));   // max over q: full r-range per batch
            mx = fmaxf(mx, __shfl_xor(mx, 32));
            int e = 0;
            if (mx > 0.f) frexpf(mx, &e);
            const float sc = ldexpf(1.0f, -e);
#pragma unroll
            for (int m = 0; m < 4; ++m)
#pragma unroll
                for (int r = 0; r < 4; ++r) wv[m][r] *= sc;
            etot += e;
        }
        uint32_t h2[4][2];
#pragma unroll
        for (int m = 0; m < 4; ++m) {
            half2_t p0 = { (_Float16)wv[m][0], (_Float16)wv[m][1] };
            half2_t p1 = { (_Float16)wv[m][2], (_Float16)wv[m][3] };
            h2[m][0] = __builtin_bit_cast(uint32_t, p0);
            h2[m][1] = __builtin_bit_cast(uint32_t, p1);
        }
        // u_kh[j] = v'[c][32kh+8q+j]; source at lane (qs,c), m = 2kh+(q>>1)
#pragma unroll
        for (int kh = 0; kh < 2; ++kh) {
            const int m0 = 2 * kh, m1 = 2 * kh + 1;
            const int a0  = __builtin_amdgcn_ds_bpermute(srcA4, (int)h2[m0][0]);
            const int a1  = __builtin_amdgcn_ds_bpermute(srcA4, (int)h2[m1][0]);
            const int a0b = __builtin_amdgcn_ds_bpermute(srcA4, (int)h2[m0][1]);
            const int a1b = __builtin_amdgcn_ds_bpermute(srcA4, (int)h2[m1][1]);
            const int b0_ = __builtin_amdgcn_ds_bpermute(srcB4, (int)h2[m0][0]);
            const int b1_ = __builtin_amdgcn_ds_bpermute(srcB4, (int)h2[m1][0]);
            const int b0b = __builtin_amdgcn_ds_bpermute(srcB4, (int)h2[m0][1]);
            const int b1b = __builtin_amdgcn_ds_bpermute(srcB4, (int)h2[m1][1]);
            uint4_t uu;
            uu[0] = (uint32_t)(msel ? a1  : a0);
            uu[1] = (uint32_t)(msel ? a1b : a0b);
            uu[2] = (uint32_t)(msel ? b1_ : b0_);
            uu[3] = (uint32_t)(msel ? b1b : b0b);
            if (kh == 0) u0 = __builtin_bit_cast(half8_t, uu);
            else         u1 = __builtin_bit_cast(half8_t, uu);
        }
    };

    WAITV(0);   // site 0 resident in ldsG[0]

    for (int s = 0; s < NSITES; ++s) {
        // prefetch next site into the other buffer. Safe vs readers: every
        // ds_read of the buffer being overwritten was drained by the previous
        // site's per-phase lgkmcnt(0); DMA data lands >=200cy after issue.
        const int sn = (s + 1 < NSITES) ? s + 1 : NSITES - 1;   // tail dup: drained, never read
        STAGE(sn, cur ^ 1);

        const float4_t xnA = *(const float4_t*)(x + (size_t)ba * 512 + (s + 2) * 4);
        const float4_t xnB = *(const float4_t*)(x + (size_t)bb * 512 + (s + 2) * 4);

        const uint32_t lb = cur ? lds1 : lds0;
        float4_t accA[4][4], accB[4][4];
#pragma unroll
        for (int f = 0; f < 4; ++f) {
            // frag n_f = (f*2+kh)*4 + m at LDS byte n_f*1024 + lane*16
            half8_t g[8];
#pragma unroll
            for (int m = 0; m < 4; ++m) {
                lread(g[m],     lb, ((f * 2 + 0) * 4 + m) * 1024);
                lread(g[4 + m], lb, ((f * 2 + 1) * 4 + m) * 1024);
            }
            WAITL();                              // 8 reads retired
            __builtin_amdgcn_sched_barrier(0);    // rule #18: pin MFMAs below
#pragma unroll
            for (int m = 0; m < 4; ++m) {
                float4_t zA = {0.f, 0.f, 0.f, 0.f};
                zA = __builtin_amdgcn_mfma_f32_16x16x32_f16(g[m],     u0A, zA, 0, 0, 0);
                zA = __builtin_amdgcn_mfma_f32_16x16x32_f16(g[4 + m], u1A, zA, 0, 0, 0);
                accA[f][m] = zA;
                float4_t zB = {0.f, 0.f, 0.f, 0.f};
                zB = __builtin_amdgcn_mfma_f32_16x16x32_f16(g[m],     u0B, zB, 0, 0, 0);
                zB = __builtin_amdgcn_mfma_f32_16x16x32_f16(g[4 + m], u1B, zB, 0, 0, 0);
                accB[f][m] = zB;
            }
        }
        EPI(s, accA, xhA, u0A, u1A, etA);
        EPI(s, accB, xhB, u0B, u1B, etB);
        xhA = xnA;
        xhB = xnB;

        WAITV(0);   // next site's DMA complete; flip buffers
        cur ^= 1;
    }

    // out[b] = 2^etot * sum_r v[b][r] * (last[r,:] . x[b,127,:])
    auto FIN = [&](const half8_t& u0, const half8_t& u1, int etot, int b) {
        const float4_t xl = *(const float4_t*)(x + (size_t)b * 512 + 508);
        float dot = 0.f;
#pragma unroll
        for (int j = 0; j < 8; ++j) {
            const int r0 = 8 * q + j, r1 = 32 + 8 * q + j;
            const float4_t l0 = *(const float4_t*)(last + r0 * 4);
            const float4_t l1 = *(const float4_t*)(last + r1 * 4);
            const float lv0 = l0[0] * xl[0] + l0[1] * xl[1] + l0[2] * xl[2] + l0[3] * xl[3];
            const float lv1 = l1[0] * xl[0] + l1[1] * xl[1] + l1[2] * xl[2] + l1[3] * xl[3];
            dot += (float)u0[j] * lv0 + (float)u1[j] * lv1;
        }
        dot += __shfl_xor(dot, 16);   // sum over q: covers r = 0..63
        dot += __shfl_xor(dot, 32);
        if (q == 0) out[b] = ldexpf(dot, etot);
    };
    FIN(u0A, u1A, etA, ba);
    FIN(u0B, u1B, etB, bb);
}

extern "C" void kernel_launch(void* const* d_in, const int* in_sizes, int n_in,
                              void* d_out, int out_size, void* d_ws, size_t ws_size,
                              hipStream_t stream) {
    (void)in_sizes; (void)n_in; (void)out_size; (void)ws_size;
    const float* x     = (const float*)d_in[0];
    const float* first = (const float*)d_in[1];
    const float* mid   = (const float*)d_in[2];
    const float* last  = (const float*)d_in[3];
    float* out = (float*)d_out;
    _Float16* gt = (_Float16*)d_ws;   // 126*2048*16 B = 4,128,768 B

    repack_g<<<1008, 256, 0, stream>>>(mid, gt);
    tt_chain<<<128, 64, 0, stream>>>(x, first, last, gt, out);
}

// Round 8
// 120.752 us; speedup vs baseline: 2.0998x; 2.0975x over previous
//
#include <hip/hip_runtime.h>
#include <stdint.h>

// BATCH=4096, LENGTH=128, FEAT=4, RANK=64, 126 mid sites.
#define NSITES 126
#define XPITCH 516                 // xbuf row pitch (floats)
#define VPH    72                  // vbuf row pitch (halfs): 144B rows -> c*VPH
                                   // half8 reads 16B-aligned, 8 word-accesses/bank

typedef _Float16 half8_t  __attribute__((ext_vector_type(8)));
typedef float    float4_t __attribute__((ext_vector_type(4)));

// light barrier: LDS-only drain; asm G-loads (vmcnt) stay in flight across it
#define LBAR() asm volatile("s_waitcnt lgkmcnt(0)\n\ts_barrier" ::: "memory")
// explicit wait: oldest loads complete when <=N remain outstanding
#define WAITV(N) asm volatile("s_waitcnt vmcnt(" #N ")" ::: "memory")
// zero-instruction tie: forces the 8 frag values through a volatile asm node,
// so MFMAs (pure ops) cannot be scheduled above the preceding WAITV
#define TIE8(F) asm volatile("" : "+v"(F[0]), "+v"(F[1]), "+v"(F[2]), "+v"(F[3]), \
                                  "+v"(F[4]), "+v"(F[5]), "+v"(F[6]), "+v"(F[7]))

// volatile asm load — R0's twice-proven form: full 64-bit VGPR address pair.
__device__ __forceinline__ void aload(half8_t& d, const void* p) {
    asm volatile("global_load_dwordx4 %0, %1, off" : "=v"(d) : "v"(p));
}

// ---------------------------------------------------------------------------
// Repack mid_cores fp32 [126][64][4][64] -> fp16 fragments, frag F (16B):
// element j = G[l = 32h + 8q + j][n = i*64 + w*16 + c], lane = 16q + c,
// F = ((i*2+h)*4 + w)*64 + lane  (+ s*2048). HW-verified (R0/R3/R7 passes).
// Pure streaming gather, one thread per fragment.
// ---------------------------------------------------------------------------
__global__ __launch_bounds__(256) void repack_g(const float* __restrict__ mid,
                                                _Float16* __restrict__ gt) {
    const int F = blockIdx.x * 256 + threadIdx.x;          // 0..258047 == 126*2048
    const int lane = F & 63, w = (F >> 6) & 3, h = (F >> 8) & 1, i = (F >> 9) & 3;
    const int s = F >> 11;
    const int q = lane >> 4, c = lane & 15;
    const float* src = mid + (size_t)s * 16384 + (32 * h + 8 * q) * 256 + i * 64 + w * 16 + c;
    half8_t o;
#pragma unroll
    for (int j = 0; j < 8; ++j) o[j] = (_Float16)src[j * 256];
    ((half8_t*)gt)[F] = o;
}

// ---------------------------------------------------------------------------
// Main chain: 256 blocks x 256 threads (1 block/CU, 16 batches/CU, 4 waves
// on 4 SIMDs) — R0's verified structure. Wave w owns r-cols [16w,16w+16).
// G fragments held in VGPRs, loaded by volatile-asm global loads with a
// 2-site prefetch pipeline and manual vmcnt(16) waits. One lgkm-only barrier
// per site for the v' exchange.
// R8 deltas vs R0 (each independently validated):
//  - vbuf is fp16 (R1 numerics: same rounding count; A-read = 2 ds_read_b128,
//    uniform bank coverage; 16 cvts/site deleted; v-write bytes halved)
//  - A-frag + x reads hoisted ABOVE WAITV(16): their LDS latency hides under
//    the G-wait (they depend only on the previous site's LBAR)
// ---------------------------------------------------------------------------
__global__ __launch_bounds__(256) void tt_chain(
    const float* __restrict__ x,      // [4096][128][4]
    const float* __restrict__ first,  // [4][64]
    const float* __restrict__ last,   // [64][4]
    const _Float16* __restrict__ gt,  // frag-ordered fp16, 32 KB/site
    float* __restrict__ out) {        // [4096]

    __shared__ __align__(16) _Float16 vbuf[2][16 * VPH];
    __shared__ float xbuf[16 * XPITCH];
    __shared__ int   eacc[16];

    const int tid  = threadIdx.x;
    const int w    = tid >> 6;
    const int lane = tid & 63;
    const int q    = lane >> 4;
    const int c    = lane & 15;
    const int b0   = blockIdx.x * 16;

    // stage x: 16 rows x 512 floats, coalesced
    {
        const int bb = tid >> 4, seg = tid & 15;
        const float4_t* src = (const float4_t*)(x + (size_t)(b0 + bb) * 512 + seg * 32);
        float4_t* dst = (float4_t*)(xbuf + bb * XPITCH + seg * 32);
#pragma unroll
        for (int k = 0; k < 8; ++k) dst[k] = src[k];
    }
    if (tid < 16) eacc[tid] = 0;
    __syncthreads();

    // v0[b,r] = sum_i x[b,0,i] * first[i,r]  (fp16 store)
    {
        const int bb = tid >> 4, rq = tid & 15;
        const float xs0 = xbuf[bb * XPITCH + 0], xs1 = xbuf[bb * XPITCH + 1];
        const float xs2 = xbuf[bb * XPITCH + 2], xs3 = xbuf[bb * XPITCH + 3];
#pragma unroll
        for (int k = 0; k < 4; ++k) {
            const int r = rq * 4 + k;
            vbuf[0][bb * VPH + r] = (_Float16)(
                xs0 * first[r] + xs1 * first[64 + r] + xs2 * first[128 + r] + xs3 * first[192 + r]);
        }
    }

    // G register pipeline: per wave 8 frags/site at byte offset
    // s*32768 + ih*4096 + w*1024 + lane*16
    half8_t F0[8], F1[8], F2[8];
    const char* gbase = (const char*)gt + w * 1024 + lane * 16;
    auto LOAD = [&](int s, half8_t* F) {
        const char* p = gbase + (size_t)s * 32768;
#pragma unroll
        for (int ih = 0; ih < 8; ++ih) aload(F[ih], p + ih * 4096);
    };
    LOAD(0, F0);    // outstanding: 8
    LOAD(1, F1);    // outstanding: 16
    LBAR();         // vbuf[0] visible (lgkm only; G loads stay in flight)

    auto STEP = [&](int s, half8_t* F) {
        const int p = s & 1;

        // A-frags + x issued BEFORE the G-wait: depend only on the previous
        // site's LBAR, so their LDS latency hides under WAITV(16).
        const _Float16* vr = &vbuf[p][c * VPH];
        half8_t af0 = *(const half8_t*)(vr + q * 8);          // v[c][8q..8q+7]
        half8_t af1 = *(const half8_t*)(vr + 32 + q * 8);     // v[c][32+8q..]
        float4_t xs[4];
#pragma unroll
        for (int jj = 0; jj < 4; ++jj)
            xs[jj] = *(const float4_t*)(xbuf + (q * 4 + jj) * XPITCH + (s + 1) * 4);

        // invariant: 24 outstanding here; oldest 8 = this site's frags
        WAITV(16);
        TIE8(F);

        // wave-local per-batch power-of-2 renorm every 8 sites (f32 unpack)
        if ((s & 7) == 0 && s != 0) {
            float a[16];
#pragma unroll
            for (int k = 0; k < 8; ++k) { a[k] = (float)af0[k]; a[8 + k] = (float)af1[k]; }
            float m = 0.f;
#pragma unroll
            for (int k = 0; k < 16; ++k) m = fmaxf(m, fabsf(a[k]));
            m = fmaxf(m, __shfl_xor(m, 16));   // max over q: all 64 r per batch
            m = fmaxf(m, __shfl_xor(m, 32));
            int e = 0;
            if (m > 0.f) frexpf(m, &e);
            const float sc = ldexpf(1.0f, -e);
#pragma unroll
            for (int k = 0; k < 8; ++k) {
                af0[k] = (_Float16)(a[k] * sc);
                af1[k] = (_Float16)(a[8 + k] * sc);
            }
            if (tid < 16) eacc[tid] += e;   // wave 0, q=0: lane==c==batch
        }

        float4_t acc[4];
#pragma unroll
        for (int i = 0; i < 4; ++i) {
            float4_t z = {0.f, 0.f, 0.f, 0.f};
            z = __builtin_amdgcn_mfma_f32_16x16x32_f16(af0, F[i * 2 + 0], z, 0, 0, 0);
            z = __builtin_amdgcn_mfma_f32_16x16x32_f16(af1, F[i * 2 + 1], z, 0, 0, 0);
            acc[i] = z;
        }

#pragma unroll
        for (int jj = 0; jj < 4; ++jj) {
            const float vn = xs[jj].x * acc[0][jj] + xs[jj].y * acc[1][jj] +
                             xs[jj].z * acc[2][jj] + xs[jj].w * acc[3][jj];
            vbuf[p ^ 1][(q * 4 + jj) * VPH + w * 16 + c] = (_Float16)vn;
        }
        LBAR();
    };

    for (int s = 0; s < NSITES; s += 3) {
        const int s2 = (s + 2 < NSITES) ? s + 2 : NSITES - 1;
        const int s3 = (s + 3 < NSITES) ? s + 3 : NSITES - 1;
        const int s4 = (s + 4 < NSITES) ? s + 4 : NSITES - 1;
        LOAD(s2, F2);          // every STEP is preceded by exactly one 8-load
        STEP(s, F0);           // LOAD -> WAITV(16) invariant holds throughout
        LOAD(s3, F0);
        STEP(s + 1, F1);
        LOAD(s4, F1);
        STEP(s + 2, F2);
    }
    WAITV(0);   // drain tail (clamped re-loads of site 125)

    // final v in vbuf[0] (126 even); out[b] = 2^eacc * sum_r v*last_vec
    {
        const int bb = tid >> 4, rq = tid & 15;
        const float x0 = xbuf[bb * XPITCH + 508], x1 = xbuf[bb * XPITCH + 509];
        const float x2 = xbuf[bb * XPITCH + 510], x3 = xbuf[bb * XPITCH + 511];
        float dot = 0.f;
#pragma unroll
        for (int k = 0; k < 4; ++k) {
            const int r = rq * 4 + k;
            const float lv = last[r * 4 + 0] * x0 + last[r * 4 + 1] * x1 +
                             last[r * 4 + 2] * x2 + last[r * 4 + 3] * x3;
            dot += lv * (float)vbuf[0][bb * VPH + r];
        }
#pragma unroll
        for (int o = 8; o > 0; o >>= 1) dot += __shfl_xor(dot, o, 16);
        if (rq == 0) out[b0 + bb] = ldexpf(dot, eacc[bb]);
    }
}

extern "C" void kernel_launch(void* const* d_in, const int* in_sizes, int n_in,
                              void* d_out, int out_size, void* d_ws, size_t ws_size,
                              hipStream_t stream) {
    (void)in_sizes; (void)n_in; (void)out_size; (void)ws_size;
    const float* x     = (const float*)d_in[0];
    const float* first = (const float*)d_in[1];
    const float* mid   = (const float*)d_in[2];
    const float* last  = (const float*)d_in[3];
    float* out = (float*)d_out;
    _Float16* gt = (_Float16*)d_ws;   // 126*2048*16 B = 4,128,768 B

    repack_g<<<1008, 256, 0, stream>>>(mid, gt);
    tt_chain<<<256, 256, 0, stream>>>(x, first, last, gt, out);
}